// Round 13
// baseline (774.486 us; speedup 1.0000x reference)
//
#include <hip/hip_runtime.h>
#include <hip/hip_bf16.h>

// QuantizedLinear: out[8192,11008] = x[8192,4096] @ dequant(W)^T
// Round 13: faithful m201 8-phase port. Per phase: {ds_read THIS phase's new
// frags ∥ stage 1 half-tile → BAR → lgkm0 → setprio(1) → 16 MFMA → setprio(0)
// → BAR}; single vmcnt(4) per K-tile at p3. Quadrants (0,0)(1,0)(1,1)(0,1),
// reads 12/8/4/0. Stage stream: p0:A1(t+1)→other, p1:B1(t+1)→other,
// p2:A0(t+2)→cur(dead), p3:B0(t+2)→cur(dead).

#define IN_F   4096
#define OUT_F  11008
#define M_DIM  8192
#define NGROUP 32

typedef __bf16 bf16x8 __attribute__((ext_vector_type(8)));
typedef float  f32x4  __attribute__((ext_vector_type(4)));
typedef unsigned short u16;
typedef u16 u16x8v __attribute__((ext_vector_type(8)));

__device__ __forceinline__ u16 f2bf(float f) {
  union { float f; unsigned u; } v; v.f = f;
  unsigned u = v.u;
  return (u16)((u + 0x7fffu + ((u >> 16) & 1u)) >> 16);  // RNE
}

__device__ __forceinline__ void gload_lds16(const void* gsrc, void* ldst) {
  __builtin_amdgcn_global_load_lds(
      (const __attribute__((address_space(1))) void*)gsrc,
      (__attribute__((address_space(3))) void*)ldst, 16, 0, 0);
}

// ---------------- dequant: packed 4-bit -> bf16 W[out][in] -----------------
__global__ __launch_bounds__(256) void dequant_w(const int* __restrict__ qw,
                                                 const int* __restrict__ qz,
                                                 const float* __restrict__ sc,
                                                 u16* __restrict__ W) {
  const int total = (IN_F / 2) * OUT_F / 4;  // int4 chunks
  int stride = gridDim.x * blockDim.x;
  for (int idx = blockIdx.x * blockDim.x + threadIdx.x; idx < total; idx += stride) {
    int j = idx << 2;
    int o = j >> 11;
    int g = (j >> 6) & 31;
    float z = (float)qz[(o << 5) + g];
    float s = sc[(o << 5) + g];
    int4 q = ((const int4*)qw)[idx];
    int qs0 = q.x, qs1 = q.y, qs2 = q.z, qs3 = q.w;
    u16x8v w;
    w[0] = f2bf(((float)(qs0 & 15) - z) * s);
    w[1] = f2bf(((float)((qs0 >> 4) & 15) - z) * s);
    w[2] = f2bf(((float)(qs1 & 15) - z) * s);
    w[3] = f2bf(((float)((qs1 >> 4) & 15) - z) * s);
    w[4] = f2bf(((float)(qs2 & 15) - z) * s);
    w[5] = f2bf(((float)((qs2 >> 4) & 15) - z) * s);
    w[6] = f2bf(((float)(qs3 & 15) - z) * s);
    w[7] = f2bf(((float)((qs3 >> 4) & 15) - z) * s);
    ((u16x8v*)W)[idx] = w;
  }
}

// ---------------- x fp32 -> bf16 -------------------------------------------
__global__ __launch_bounds__(256) void cvt_x(const float* __restrict__ x,
                                             u16* __restrict__ Xb) {
  const int total = M_DIM * IN_F / 8;
  int stride = gridDim.x * blockDim.x;
  for (int idx = blockIdx.x * blockDim.x + threadIdx.x; idx < total; idx += stride) {
    float4 a = ((const float4*)x)[idx * 2];
    float4 b = ((const float4*)x)[idx * 2 + 1];
    u16x8v v;
    v[0] = f2bf(a.x); v[1] = f2bf(a.y); v[2] = f2bf(a.z); v[3] = f2bf(a.w);
    v[4] = f2bf(b.x); v[5] = f2bf(b.y); v[6] = f2bf(b.z); v[7] = f2bf(b.w);
    ((u16x8v*)Xb)[idx] = v;
  }
}

// ---------------- 256x256 bf16 GEMM, m201 8-phase: C = A * B^T -------------
// 8 waves 2Mx4N, wave tile 128x64 contiguous. Quadrant (mh,nh) = 64x32.
// Frag regs: a0_,a1_ (8 each), b0_,b1_ (4 each) = 96 VGPR; acc in AGPR.

#define BAR       __builtin_amdgcn_s_barrier()
#define SCHED0    __builtin_amdgcn_sched_barrier(0)
#define LGKM0     asm volatile("s_waitcnt lgkmcnt(0)" ::: "memory")
#define LGKM8     asm volatile("s_waitcnt lgkmcnt(8)" ::: "memory")
#define VMCNT0    asm volatile("s_waitcnt vmcnt(0)" ::: "memory")
#define VMCNT4    asm volatile("s_waitcnt vmcnt(4)" ::: "memory")
#define PRIO(p)   __builtin_amdgcn_s_setprio(p)

__global__ __launch_bounds__(512, 1) void gemm256(const u16* __restrict__ A,
                                                  const u16* __restrict__ B,
                                                  float* __restrict__ C) {
  constexpr int K = IN_F, N = OUT_F;
  constexpr int NT = K / 64;  // 64 K-tiles
  __shared__ __align__(16) u16 sA[2][256 * 64];
  __shared__ __align__(16) u16 sB[2][256 * 64];

  const int NTN = OUT_F / 256;           // 43
  const int NWG = (M_DIM / 256) * NTN;   // 1376 (divisible by 8)
  int bid = blockIdx.x;
  int wg  = (bid & 7) * (NWG / 8) + (bid >> 3);  // bijective XCD swizzle
  int tm = wg / NTN, tn = wg - tm * NTN;
  int m0 = tm * 256, n0 = tn * 256;

  int tid  = threadIdx.x;
  int lane = tid & 63;
  int wave = tid >> 6;
  int wr = wave >> 2, wc = wave & 3;

  // staging: thread covers row (tid>>3) of a 64-row issue, phys 16B slot tid&7.
  // phys slot s at row r holds global col-slot s^(r&7)  (involution).
  int rstage = tid >> 3;                               // 0..63
  int gslot  = ((tid & 7) ^ (rstage & 7)) << 3;        // global col elem
  int ldsoff = rstage * 64 + ((tid & 7) << 3);         // linear LDS elem
  const u16* Ag = A + (size_t)(m0 + rstage) * K + gslot;
  const u16* Bg = B + (size_t)(n0 + rstage) * K + gslot;

  // one half-tile (128 rows) = 2 gloads
#define STAGE_A(cb, h, kt) do {                                   \
    const u16* _g = Ag + (size_t)(h) * 128 * K + (kt) * 64;       \
    u16* _l = sA[cb] + (h) * 128 * 64 + ldsoff;                   \
    gload_lds16(_g, _l);                                          \
    gload_lds16(_g + (size_t)64 * K, _l + 64 * 64);               \
  } while (0)

#define STAGE_B(cb, h, kt) do {                                   \
    const u16* _g = Bg + (size_t)(h) * 128 * K + (kt) * 64;       \
    u16* _l = sB[cb] + (h) * 128 * 64 + ldsoff;                   \
    gload_lds16(_g, _l);                                          \
    gload_lds16(_g + (size_t)64 * K, _l + 64 * 64);               \
  } while (0)

  // fragment reads: lane row base+(lane&15), k-quad q8=lane>>4, slice ks.
  // phys 16B slot = (ks*4+q8) ^ (lane&7)  (all row bases are multiples of 16)
  int q8  = lane >> 4;
  int sl0 = ((q8 ^ (lane & 7)) << 3);            // ks=0, elems
  int sl1 = (((q8 | 4) ^ (lane & 7)) << 3);      // ks=1
  int abase = (wr * 128 + (lane & 15)) * 64;     // wave rows wr*128..+127
  int bbase = (wc * 64 + (lane & 15)) * 64;      // wave cols wc*64..+63

  bf16x8 a0_[8], a1_[8], b0_[4], b1_[4];
  f32x4 acc[8][4] = {};

  // a-frags of quadrant row-half mh: dst[mf*2+ks]
#define LDA_H(cb, mh, dst) do {                                   \
    const u16* _p = sA[cb] + abase + (mh) * 4096;                 \
    _Pragma("unroll") for (int mf = 0; mf < 4; mf++) {            \
      dst[mf*2+0] = *(const bf16x8*)(_p + mf * 1024 + sl0);       \
      dst[mf*2+1] = *(const bf16x8*)(_p + mf * 1024 + sl1);       \
    }                                                             \
  } while (0)

  // b-frags of quadrant col-half nh: dst[nf*2+ks]
#define LDB_H(cb, nh, dst) do {                                   \
    const u16* _p = sB[cb] + bbase + (nh) * 2048;                 \
    _Pragma("unroll") for (int nf = 0; nf < 2; nf++) {            \
      dst[nf*2+0] = *(const bf16x8*)(_p + nf * 1024 + sl0);       \
      dst[nf*2+1] = *(const bf16x8*)(_p + nf * 1024 + sl1);       \
    }                                                             \
  } while (0)

  // 16 MFMA of quadrant (mh,nh), ks-outer (same-acc dep distance 8)
#define QUAD16(aq, bq, mh, nh) do {                                            \
    _Pragma("unroll") for (int mf = 0; mf < 4; mf++)                           \
      _Pragma("unroll") for (int nf = 0; nf < 2; nf++)                         \
        acc[(mh)*4+mf][(nh)*2+nf] = __builtin_amdgcn_mfma_f32_16x16x32_bf16(   \
            aq[mf*2+0], bq[nf*2+0], acc[(mh)*4+mf][(nh)*2+nf], 0, 0, 0);       \
    _Pragma("unroll") for (int mf = 0; mf < 4; mf++)                           \
      _Pragma("unroll") for (int nf = 0; nf < 2; nf++)                         \
        acc[(mh)*4+mf][(nh)*2+nf] = __builtin_amdgcn_mfma_f32_16x16x32_bf16(   \
            aq[mf*2+1], bq[nf*2+1], acc[(mh)*4+mf][(nh)*2+nf], 0, 0, 0);       \
  } while (0)

  // One K-tile t, cur buf c. Liveness: A-regions of cur die after p1-close
  // (a0@p0, a1@p1 drained by each wave's LGKM0 pre-p1-close-BAR); B-regions
  // die after p2-close (b0@p0, b1@p2). vmcnt(4) at p3 drains ALL of t+1
  // (A0,B0 staged t-1.p2/p3; A1,B1 staged t.p0/p1), leaves A0,B0(t+2).
#define TILE4(c, t) do {                                          \
    int _k1 = ((t) + 1) & (NT - 1), _k2 = ((t) + 2) & (NT - 1);   \
    /* p0: quadrant (0,0); reads a0,b0 (12); stage A1(t+1)->other */ \
    LDA_H(c, 0, a0_); LDB_H(c, 0, b0_);                           \
    STAGE_A((c) ^ 1, 1, _k1);                                     \
    LGKM8; BAR; LGKM0;                                            \
    PRIO(1); QUAD16(a0_, b0_, 0, 0); PRIO(0); BAR;                \
    /* p1: (1,0); reads a1 (8); stage B1(t+1)->other */           \
    LDA_H(c, 1, a1_);                                             \
    STAGE_B((c) ^ 1, 1, _k1);                                     \
    BAR; LGKM0;                                                   \
    PRIO(1); QUAD16(a1_, b0_, 1, 0); PRIO(0); BAR;                \
    /* p2: (1,1); reads b1 (4); stage A0(t+2)->cur (A dead) */    \
    LDB_H(c, 1, b1_);                                             \
    STAGE_A(c, 0, _k2);                                           \
    BAR; LGKM0;                                                   \
    PRIO(1); QUAD16(a1_, b1_, 1, 1); PRIO(0); BAR;                \
    /* p3: (0,1); stage B0(t+2)->cur (B dead); tile-end wait */   \
    STAGE_B(c, 0, _k2);                                           \
    BAR;                                                          \
    PRIO(1); QUAD16(a0_, b1_, 0, 1); PRIO(0);                     \
    VMCNT4; BAR;                                                  \
  } while (0)

  // prologue: tile0 (4 halves) -> buf0; A0,B0 of tile1 -> buf1; vmcnt(4)
  // leaves exactly {A0,B0}(t1) in flight (steady-state invariant); BAR.
  STAGE_A(0, 0, 0); STAGE_A(0, 1, 0);
  STAGE_B(0, 0, 0); STAGE_B(0, 1, 0);
  STAGE_A(1, 0, 1); STAGE_B(1, 0, 1);
  VMCNT4; BAR;
  SCHED0;
  asm volatile("" ::: "memory");

#pragma unroll 1
  for (int t = 0; t < NT; t += 2) {
    TILE4(0, t);
    TILE4(1, t + 1);
  }

  // C/D layout: col = lane&15, row = (lane>>4)*4 + j
  // out row = m0 + wr*128 + MF*16 + (lane>>4)*4 + j
  // out col = n0 + wc*64  + NF*16 + (lane&15)
  float* Cp = C + (size_t)(m0 + wr * 128 + ((lane >> 4) << 2)) * N
                + n0 + wc * 64 + (lane & 15);
#pragma unroll
  for (int mf = 0; mf < 8; mf++)
#pragma unroll
    for (int nf = 0; nf < 4; nf++)
#pragma unroll
      for (int j = 0; j < 4; j++)
        Cp[(size_t)(mf * 16 + j) * N + nf * 16] = acc[mf][nf][j];
}

// ---------------- exact fp32 fallback (only if ws too small) ---------------
__global__ __launch_bounds__(256) void naive_gemm(const float* __restrict__ x,
                                                  const int* __restrict__ qw,
                                                  const int* __restrict__ qz,
                                                  const float* __restrict__ sc,
                                                  float* __restrict__ out) {
  __shared__ float xs[IN_F];
  int m = blockIdx.y;
  int n = blockIdx.x * 256 + threadIdx.x;
  for (int i = threadIdx.x; i < IN_F; i += 256) xs[i] = x[(size_t)m * IN_F + i];
  __syncthreads();
  float acc = 0.f;
  const int* qrow = qw + (size_t)n * (IN_F / 2);
  for (int g = 0; g < NGROUP; g++) {
    float z = (float)qz[n * NGROUP + g];
    float s = sc[n * NGROUP + g];
    for (int t = 0; t < 64; t++) {
      int q = qrow[g * 64 + t];
      acc += xs[g * 128 + 2 * t] * ((float)(q & 15) - z) * s;
      acc += xs[g * 128 + 2 * t + 1] * ((float)((q >> 4) & 15) - z) * s;
    }
  }
  out[(size_t)m * OUT_F + n] = acc;
}

extern "C" void kernel_launch(void* const* d_in, const int* in_sizes, int n_in,
                              void* d_out, int out_size, void* d_ws, size_t ws_size,
                              hipStream_t stream) {
  const float* x  = (const float*)d_in[0];
  const int*   qw = (const int*)d_in[1];
  const int*   qz = (const int*)d_in[2];
  const float* sc = (const float*)d_in[3];
  float* out = (float*)d_out;

  const size_t WBYTES = (size_t)OUT_F * IN_F * 2;
  const size_t XBYTES = (size_t)M_DIM * IN_F * 2;

  if (ws_size >= WBYTES + XBYTES) {
    u16* Wb = (u16*)d_ws;
    u16* Xb = (u16*)((char*)d_ws + WBYTES);
    dequant_w<<<2048, 256, 0, stream>>>(qw, qz, sc, Wb);
    cvt_x<<<2048, 256, 0, stream>>>(x, Xb);
    gemm256<<<(M_DIM / 256) * (OUT_F / 256), 512, 0, stream>>>(Xb, Wb, out);
  } else {
    naive_gemm<<<dim3(OUT_F / 256, M_DIM), 256, 0, stream>>>(x, qw, qz, sc, out);
  }
}

// Round 14
// 773.651 us; speedup vs baseline: 1.0011x; 1.0011x over previous
//
#include <hip/hip_runtime.h>
#include <hip/hip_bf16.h>

// QuantizedLinear: out[8192,11008] = x[8192,4096] @ dequant(W)^T
// Round 14: merged single-phase K-tile — ONE barrier per tile.
// {24 ds_reads cur buf; 8 stage-gloads t+1 -> other buf; 64 MFMA ks-outer;
//  vmcnt(0)+lgkm(0) (both free by distance); BAR}. All frag regs live (96
// VGPR, proven no-spill in R13). R11 was 2 barriers+2 wait-clusters/tile.

#define IN_F   4096
#define OUT_F  11008
#define M_DIM  8192
#define NGROUP 32

typedef __bf16 bf16x8 __attribute__((ext_vector_type(8)));
typedef float  f32x4  __attribute__((ext_vector_type(4)));
typedef unsigned short u16;
typedef u16 u16x8v __attribute__((ext_vector_type(8)));

__device__ __forceinline__ u16 f2bf(float f) {
  union { float f; unsigned u; } v; v.f = f;
  unsigned u = v.u;
  return (u16)((u + 0x7fffu + ((u >> 16) & 1u)) >> 16);  // RNE
}

__device__ __forceinline__ void gload_lds16(const void* gsrc, void* ldst) {
  __builtin_amdgcn_global_load_lds(
      (const __attribute__((address_space(1))) void*)gsrc,
      (__attribute__((address_space(3))) void*)ldst, 16, 0, 0);
}

// ---------------- dequant: packed 4-bit -> bf16 W[out][in] -----------------
__global__ __launch_bounds__(256) void dequant_w(const int* __restrict__ qw,
                                                 const int* __restrict__ qz,
                                                 const float* __restrict__ sc,
                                                 u16* __restrict__ W) {
  const int total = (IN_F / 2) * OUT_F / 4;  // int4 chunks
  int stride = gridDim.x * blockDim.x;
  for (int idx = blockIdx.x * blockDim.x + threadIdx.x; idx < total; idx += stride) {
    int j = idx << 2;
    int o = j >> 11;
    int g = (j >> 6) & 31;
    float z = (float)qz[(o << 5) + g];
    float s = sc[(o << 5) + g];
    int4 q = ((const int4*)qw)[idx];
    int qs0 = q.x, qs1 = q.y, qs2 = q.z, qs3 = q.w;
    u16x8v w;
    w[0] = f2bf(((float)(qs0 & 15) - z) * s);
    w[1] = f2bf(((float)((qs0 >> 4) & 15) - z) * s);
    w[2] = f2bf(((float)(qs1 & 15) - z) * s);
    w[3] = f2bf(((float)((qs1 >> 4) & 15) - z) * s);
    w[4] = f2bf(((float)(qs2 & 15) - z) * s);
    w[5] = f2bf(((float)((qs2 >> 4) & 15) - z) * s);
    w[6] = f2bf(((float)(qs3 & 15) - z) * s);
    w[7] = f2bf(((float)((qs3 >> 4) & 15) - z) * s);
    ((u16x8v*)W)[idx] = w;
  }
}

// ---------------- x fp32 -> bf16 -------------------------------------------
__global__ __launch_bounds__(256) void cvt_x(const float* __restrict__ x,
                                             u16* __restrict__ Xb) {
  const int total = M_DIM * IN_F / 8;
  int stride = gridDim.x * blockDim.x;
  for (int idx = blockIdx.x * blockDim.x + threadIdx.x; idx < total; idx += stride) {
    float4 a = ((const float4*)x)[idx * 2];
    float4 b = ((const float4*)x)[idx * 2 + 1];
    u16x8v v;
    v[0] = f2bf(a.x); v[1] = f2bf(a.y); v[2] = f2bf(a.z); v[3] = f2bf(a.w);
    v[4] = f2bf(b.x); v[5] = f2bf(b.y); v[6] = f2bf(b.z); v[7] = f2bf(b.w);
    ((u16x8v*)Xb)[idx] = v;
  }
}

// ---------------- 256x256 bf16 GEMM, 1 barrier/K-tile: C = A * B^T ---------
// 8 waves 2Mx4N, wave tile 128x64 contiguous. Per tile t (cur buf c):
// reads buf c (24 b128) | stages t+1 -> buf c^1 (8 gloads) | 64 MFMA |
// VMCNT0 (stages drained, issued ~1240cy ago) | LGKM0 (reads long done) | BAR.
// Cross-wave: reads of c covered by t-1's VMCNT0+BAR; stage-WAR into c^1
// covered by t-1's LGKM0+BAR.

#define BAR       __builtin_amdgcn_s_barrier()
#define SCHED0    __builtin_amdgcn_sched_barrier(0)
#define LGKM0     asm volatile("s_waitcnt lgkmcnt(0)" ::: "memory")
#define VMCNT0    asm volatile("s_waitcnt vmcnt(0)" ::: "memory")
#define PRIO(p)   __builtin_amdgcn_s_setprio(p)

__global__ __launch_bounds__(512, 1) void gemm256(const u16* __restrict__ A,
                                                  const u16* __restrict__ B,
                                                  float* __restrict__ C) {
  constexpr int K = IN_F, N = OUT_F;
  constexpr int NT = K / 64;  // 64 K-tiles
  __shared__ __align__(16) u16 sA[2][256 * 64];
  __shared__ __align__(16) u16 sB[2][256 * 64];

  const int NTN = OUT_F / 256;           // 43
  const int NWG = (M_DIM / 256) * NTN;   // 1376 (divisible by 8)
  int bid = blockIdx.x;
  int wg  = (bid & 7) * (NWG / 8) + (bid >> 3);  // bijective XCD swizzle
  int tm = wg / NTN, tn = wg - tm * NTN;
  int m0 = tm * 256, n0 = tn * 256;

  int tid  = threadIdx.x;
  int lane = tid & 63;
  int wave = tid >> 6;
  int wr = wave >> 2, wc = wave & 3;

  // staging: thread covers row (tid>>3) of a 64-row issue, phys 16B slot tid&7.
  // phys slot s at row r holds global col-slot s^(r&7)  (involution).
  int rstage = tid >> 3;                               // 0..63
  int gslot  = ((tid & 7) ^ (rstage & 7)) << 3;        // global col elem
  int ldsoff = rstage * 64 + ((tid & 7) << 3);         // linear LDS elem
  const u16* Ag = A + (size_t)(m0 + rstage) * K + gslot;
  const u16* Bg = B + (size_t)(n0 + rstage) * K + gslot;

  // full K-tile stage: 4 A-gloads + 4 B-gloads (64 rows each)
#define STAGE_AB(cb, kt) do {                                     \
    const u16* _ga = Ag + (kt) * 64;                              \
    const u16* _gb = Bg + (kt) * 64;                              \
    u16* _la = sA[cb] + ldsoff;                                   \
    u16* _lb = sB[cb] + ldsoff;                                   \
    gload_lds16(_ga, _la);                                        \
    gload_lds16(_ga + (size_t)64 * K, _la + 64 * 64);             \
    gload_lds16(_ga + (size_t)128 * K, _la + 128 * 64);           \
    gload_lds16(_ga + (size_t)192 * K, _la + 192 * 64);           \
    gload_lds16(_gb, _lb);                                        \
    gload_lds16(_gb + (size_t)64 * K, _lb + 64 * 64);             \
    gload_lds16(_gb + (size_t)128 * K, _lb + 128 * 64);           \
    gload_lds16(_gb + (size_t)192 * K, _lb + 192 * 64);           \
  } while (0)

  // fragment reads: lane row base+(lane&15), k-quad q8=lane>>4, slice ks.
  // phys 16B slot = (ks*4+q8) ^ (lane&7)  (all row bases are multiples of 16)
  int q8  = lane >> 4;
  int sl0 = ((q8 ^ (lane & 7)) << 3);            // ks=0, elems
  int sl1 = (((q8 | 4) ^ (lane & 7)) << 3);      // ks=1
  int abase = (wr * 128 + (lane & 15)) * 64;     // wave rows wr*128..+127
  int bbase = (wc * 64 + (lane & 15)) * 64;      // wave cols wc*64..+63

  bf16x8 a0_[8], a1_[8], b0_[4], b1_[4];
  f32x4 acc[8][4] = {};

  // a-frags of row-half mh: dst[mf*2+ks]
#define LDA_H(cb, mh, dst) do {                                   \
    const u16* _p = sA[cb] + abase + (mh) * 4096;                 \
    _Pragma("unroll") for (int mf = 0; mf < 4; mf++) {            \
      dst[mf*2+0] = *(const bf16x8*)(_p + mf * 1024 + sl0);       \
      dst[mf*2+1] = *(const bf16x8*)(_p + mf * 1024 + sl1);       \
    }                                                             \
  } while (0)

  // b-frags of col-half nh: dst[nf*2+ks]
#define LDB_H(cb, nh, dst) do {                                   \
    const u16* _p = sB[cb] + bbase + (nh) * 2048;                 \
    _Pragma("unroll") for (int nf = 0; nf < 2; nf++) {            \
      dst[nf*2+0] = *(const bf16x8*)(_p + nf * 1024 + sl0);       \
      dst[nf*2+1] = *(const bf16x8*)(_p + nf * 1024 + sl1);       \
    }                                                             \
  } while (0)

  // 16 MFMA of quadrant (mh,nh), ks-outer (same-acc dep distance 8)
#define QUAD16(aq, bq, mh, nh) do {                                            \
    _Pragma("unroll") for (int mf = 0; mf < 4; mf++)                           \
      _Pragma("unroll") for (int nf = 0; nf < 2; nf++)                         \
        acc[(mh)*4+mf][(nh)*2+nf] = __builtin_amdgcn_mfma_f32_16x16x32_bf16(   \
            aq[mf*2+0], bq[nf*2+0], acc[(mh)*4+mf][(nh)*2+nf], 0, 0, 0);       \
    _Pragma("unroll") for (int mf = 0; mf < 4; mf++)                           \
      _Pragma("unroll") for (int nf = 0; nf < 2; nf++)                         \
        acc[(mh)*4+mf][(nh)*2+nf] = __builtin_amdgcn_mfma_f32_16x16x32_bf16(   \
            aq[mf*2+1], bq[nf*2+1], acc[(mh)*4+mf][(nh)*2+nf], 0, 0, 0);       \
  } while (0)

  // one K-tile, one barrier.
#define TILE(c, t) do {                                           \
    int _k1 = ((t) + 1) & (NT - 1);                               \
    LDA_H(c, 0, a0_); LDB_H(c, 0, b0_);                           \
    LDA_H(c, 1, a1_); LDB_H(c, 1, b1_);                           \
    STAGE_AB((c) ^ 1, _k1);                                       \
    PRIO(1);                                                      \
    QUAD16(a0_, b0_, 0, 0);                                       \
    QUAD16(a0_, b1_, 0, 1);                                       \
    QUAD16(a1_, b0_, 1, 0);                                       \
    QUAD16(a1_, b1_, 1, 1);                                       \
    PRIO(0);                                                      \
    VMCNT0; LGKM0; BAR;                                           \
  } while (0)

  // prologue: stage tile0 -> buf0, drain, barrier.
  STAGE_AB(0, 0);
  VMCNT0; BAR;
  SCHED0;
  asm volatile("" ::: "memory");

#pragma unroll 1
  for (int t = 0; t < NT; t += 2) {
    TILE(0, t);
    TILE(1, t + 1);
  }

  // C/D layout: col = lane&15, row = (lane>>4)*4 + j
  // out row = m0 + wr*128 + mf*16 + (lane>>4)*4 + j
  // out col = n0 + wc*64  + nf*16 + (lane&15)
  float* Cp = C + (size_t)(m0 + wr * 128 + ((lane >> 4) << 2)) * N
                + n0 + wc * 64 + (lane & 15);
#pragma unroll
  for (int mf = 0; mf < 8; mf++)
#pragma unroll
    for (int nf = 0; nf < 4; nf++)
#pragma unroll
      for (int j = 0; j < 4; j++)
        Cp[(size_t)(mf * 16 + j) * N + nf * 16] = acc[mf][nf][j];
}

// ---------------- exact fp32 fallback (only if ws too small) ---------------
__global__ __launch_bounds__(256) void naive_gemm(const float* __restrict__ x,
                                                  const int* __restrict__ qw,
                                                  const int* __restrict__ qz,
                                                  const float* __restrict__ sc,
                                                  float* __restrict__ out) {
  __shared__ float xs[IN_F];
  int m = blockIdx.y;
  int n = blockIdx.x * 256 + threadIdx.x;
  for (int i = threadIdx.x; i < IN_F; i += 256) xs[i] = x[(size_t)m * IN_F + i];
  __syncthreads();
  float acc = 0.f;
  const int* qrow = qw + (size_t)n * (IN_F / 2);
  for (int g = 0; g < NGROUP; g++) {
    float z = (float)qz[n * NGROUP + g];
    float s = sc[n * NGROUP + g];
    for (int t = 0; t < 64; t++) {
      int q = qrow[g * 64 + t];
      acc += xs[g * 128 + 2 * t] * ((float)(q & 15) - z) * s;
      acc += xs[g * 128 + 2 * t + 1] * ((float)((q >> 4) & 15) - z) * s;
    }
  }
  out[(size_t)m * OUT_F + n] = acc;
}

extern "C" void kernel_launch(void* const* d_in, const int* in_sizes, int n_in,
                              void* d_out, int out_size, void* d_ws, size_t ws_size,
                              hipStream_t stream) {
  const float* x  = (const float*)d_in[0];
  const int*   qw = (const int*)d_in[1];
  const int*   qz = (const int*)d_in[2];
  const float* sc = (const float*)d_in[3];
  float* out = (float*)d_out;

  const size_t WBYTES = (size_t)OUT_F * IN_F * 2;
  const size_t XBYTES = (size_t)M_DIM * IN_F * 2;

  if (ws_size >= WBYTES + XBYTES) {
    u16* Wb = (u16*)d_ws;
    u16* Xb = (u16*)((char*)d_ws + WBYTES);
    dequant_w<<<2048, 256, 0, stream>>>(qw, qz, sc, Wb);
    cvt_x<<<2048, 256, 0, stream>>>(x, Xb);
    gemm256<<<(M_DIM / 256) * (OUT_F / 256), 512, 0, stream>>>(Xb, Wb, out);
  } else {
    naive_gemm<<<dim3(OUT_F / 256, M_DIM), 256, 0, stream>>>(x, qw, qz, sc, out);
  }
}